// Round 1
// baseline (283.978 us; speedup 1.0000x reference)
//
#include <hip/hip_runtime.h>

#define NV 2052
#define KD 512
#define RTOT 2564
#define RPAD 2688
#define JTOT 8192

// workspace float offsets
#define OFF_DCT   0u
#define OFF_DCTT  1050624u
#define OFF_M1    2101248u
#define OFF_MT    2166784u
#define OFF_ZT    2510848u
#define OFF_RP    3559424u
#define OFF_IP    3821568u
#define OFF_A     4083712u
#define OFF_X     4100096u
#define OFF_AX    4116480u
#define OFF_HG    4132864u
#define OFF_CC    OFF_DCT   // reuse dct region after M1/M2 are built
#define OFF_SS    OFF_DCTT

#define SREC_OFF  4194304u
#define AAUG_OFF  21004288u

// ---------- build DCT (512 x 2052) and transpose ----------
__global__ __launch_bounds__(256) void k_dct(float* __restrict__ dct, float* __restrict__ dctT) {
    int g = blockIdx.x * 256 + threadIdx.x;
    if (g >= KD * NV) return;
    int k = g / NV;
    int v = g - k * NV;
    float val;
    if (k == 0) {
        val = 1.0f / sqrtf(2052.0f);
    } else {
        int m = (2 * v + 1) * k;
        int r = m % 8208;                       // exact arg reduction mod 2*pi
        float ang = (float)((double)r * (3.14159265358979323846 / 4104.0));
        val = sqrtf(2.0f / 2052.0f) * cosf(ang);
    }
    dct[k * NV + v] = val;
    dctT[v * KD + k] = val;
}

// ---------- M1 = dct @ LF  (512 x 128); also write transposed into MT ----------
__global__ __launch_bounds__(256) void k_m1(const float* __restrict__ dct, const float* __restrict__ LF,
                                            float* __restrict__ M1, float* __restrict__ MT) {
    int g = blockIdx.x * 256 + threadIdx.x;   // 16384 threads
    int t = g & 127;
    int k0 = (g >> 7) * 4;
    float a0 = 0.f, a1 = 0.f, a2 = 0.f, a3 = 0.f;
    const float* d0 = dct + (size_t)(k0 + 0) * NV;
    const float* d1 = dct + (size_t)(k0 + 1) * NV;
    const float* d2 = dct + (size_t)(k0 + 2) * NV;
    const float* d3 = dct + (size_t)(k0 + 3) * NV;
    for (int v = 0; v < NV; ++v) {
        float lf = LF[v * 128 + t];
        a0 += d0[v] * lf; a1 += d1[v] * lf; a2 += d2[v] * lf; a3 += d3[v] * lf;
    }
    M1[(k0 + 0) * 128 + t] = a0; M1[(k0 + 1) * 128 + t] = a1;
    M1[(k0 + 2) * 128 + t] = a2; M1[(k0 + 3) * 128 + t] = a3;
    MT[t * RPAD + k0 + 0] = a0; MT[t * RPAD + k0 + 1] = a1;
    MT[t * RPAD + k0 + 2] = a2; MT[t * RPAD + k0 + 3] = a3;
}

// ---------- M2 = dctT @ M1 (2052 x 128), written transposed into MT cols 512.. ----------
__global__ __launch_bounds__(256) void k_m2(const float* __restrict__ dctT, const float* __restrict__ M1,
                                            float* __restrict__ MT) {
    int g = blockIdx.x * 256 + threadIdx.x;
    if (g >= 513 * 128) return;
    int t = g & 127;
    int v0 = (g >> 7) * 4;
    float a0 = 0.f, a1 = 0.f, a2 = 0.f, a3 = 0.f;
    const float* q0 = dctT + (size_t)(v0 + 0) * KD;
    const float* q1 = dctT + (size_t)(v0 + 1) * KD;
    const float* q2 = dctT + (size_t)(v0 + 2) * KD;
    const float* q3 = dctT + (size_t)(v0 + 3) * KD;
    for (int k = 0; k < KD; ++k) {
        float m = M1[k * 128 + t];
        a0 += q0[k] * m; a1 += q1[k] * m; a2 += q2[k] * m; a3 += q3[k] * m;
    }
    MT[t * RPAD + KD + v0 + 0] = a0; MT[t * RPAD + KD + v0 + 1] = a1;
    MT[t * RPAD + KD + v0 + 2] = a2; MT[t * RPAD + KD + v0 + 3] = a3;
}

// ---------- zero MT pad columns 2564..2687 ----------
__global__ void k_pad(float* __restrict__ MT) {
    int t = blockIdx.x;
    int c = threadIdx.x;
    if (c < RPAD - RTOT) MT[t * RPAD + RTOT + c] = 0.f;
}

// ---------- ZT[t][j] = zflat[j][t]  (transpose 8192x128 -> 128x8192) ----------
__global__ __launch_bounds__(256) void k_zt(const float* __restrict__ z, float* __restrict__ ZT) {
    __shared__ float tile[32][33];
    int j0 = blockIdx.x * 32, t0 = blockIdx.y * 32;
    int tx = threadIdx.x, ty = threadIdx.y;  // (32,8)
    #pragma unroll
    for (int k = 0; k < 4; ++k)
        tile[ty + 8 * k][tx] = z[(size_t)(j0 + ty + 8 * k) * 128 + t0 + tx];
    __syncthreads();
    #pragma unroll
    for (int k = 0; k < 4; ++k)
        ZT[(size_t)(t0 + ty + 8 * k) * JTOT + j0 + tx] = tile[tx][ty + 8 * k];
}

// ---------- big GEMM: C[r][j] = sum_t MT[t][r] * ZT[t][j], scattered to out ----------
__global__ __launch_bounds__(256) void k_gemm(const float* __restrict__ MT, const float* __restrict__ ZT,
                                              float* __restrict__ out) {
    __shared__ float As[32][132];
    __shared__ float Bs[32][132];
    const int tid = threadIdx.x;
    const int tx = tid & 15;
    const int ty = tid >> 4;
    const int j0 = blockIdx.x * 128;
    const int r0 = blockIdx.y * 128;
    const int lk = tid >> 3;          // 0..31
    const int lm = (tid & 7) * 16;    // 0..112
    float acc[8][8];
    #pragma unroll
    for (int i = 0; i < 8; ++i)
        #pragma unroll
        for (int j = 0; j < 8; ++j) acc[i][j] = 0.f;

    for (int kc = 0; kc < 128; kc += 32) {
        const float* pa = MT + (size_t)(kc + lk) * RPAD + r0 + lm;
        const float* pb = ZT + (size_t)(kc + lk) * JTOT + j0 + lm;
        float4 A0 = *(const float4*)(pa + 0);
        float4 A1 = *(const float4*)(pa + 4);
        float4 A2 = *(const float4*)(pa + 8);
        float4 A3 = *(const float4*)(pa + 12);
        float4 B0 = *(const float4*)(pb + 0);
        float4 B1 = *(const float4*)(pb + 4);
        float4 B2 = *(const float4*)(pb + 8);
        float4 B3 = *(const float4*)(pb + 12);
        __syncthreads();
        *(float4*)&As[lk][lm + 0] = A0;  *(float4*)&As[lk][lm + 4] = A1;
        *(float4*)&As[lk][lm + 8] = A2;  *(float4*)&As[lk][lm + 12] = A3;
        *(float4*)&Bs[lk][lm + 0] = B0;  *(float4*)&Bs[lk][lm + 4] = B1;
        *(float4*)&Bs[lk][lm + 8] = B2;  *(float4*)&Bs[lk][lm + 12] = B3;
        __syncthreads();
        #pragma unroll
        for (int kk = 0; kk < 32; ++kk) {
            float4 a0 = *(const float4*)&As[kk][ty * 8];
            float4 a1 = *(const float4*)&As[kk][ty * 8 + 4];
            float4 b0 = *(const float4*)&Bs[kk][tx * 8];
            float4 b1 = *(const float4*)&Bs[kk][tx * 8 + 4];
            float av[8] = {a0.x, a0.y, a0.z, a0.w, a1.x, a1.y, a1.z, a1.w};
            float bv[8] = {b0.x, b0.y, b0.z, b0.w, b1.x, b1.y, b1.z, b1.w};
            #pragma unroll
            for (int i = 0; i < 8; ++i)
                #pragma unroll
                for (int j = 0; j < 8; ++j)
                    acc[i][j] += av[i] * bv[j];
        }
    }
    const unsigned bb = (unsigned)blockIdx.x;  // batch index (j0>>7)
    #pragma unroll
    for (int im = 0; im < 8; ++im) {
        int r = r0 + ty * 8 + im;
        if (r < RTOT) {
            unsigned base;
            if (r < KD) base = bb * 65536u + (unsigned)r * 128u;
            else        base = SREC_OFF + bb * 262656u + (unsigned)(r - KD) * 128u;
            float4 w0 = make_float4(acc[im][0], acc[im][1], acc[im][2], acc[im][3]);
            float4 w1 = make_float4(acc[im][4], acc[im][5], acc[im][6], acc[im][7]);
            *(float4*)(out + base + tx * 8 + 0) = w0;
            *(float4*)(out + base + tx * 8 + 4) = w1;
        }
    }
}

// ---------- Hilbert (circular conv with cot kernel) -> cos/sin of phase ----------
__global__ __launch_bounds__(128) void k_hilb(const float* __restrict__ z,
                                              float* __restrict__ Cc, float* __restrict__ Ss) {
    __shared__ float zr[128];
    __shared__ float h[128];
    int row = blockIdx.x;
    int t = threadIdx.x;
    zr[t] = z[(size_t)row * 128 + t];
    float hv = 0.f;
    if (t & 1) {
        float ang = 3.14159265358979323846f * (float)t * (1.0f / 128.0f);
        hv = (cosf(ang) / sinf(ang)) * (1.0f / 64.0f);
    }
    h[t] = hv;
    __syncthreads();
    float acc = 0.f;
    #pragma unroll 8
    for (int i = 0; i < 64; ++i) {
        int d = 2 * i + 1;
        acc += h[d] * zr[(t - d) & 127];
    }
    float zv = zr[t];
    float inv = rsqrtf(zv * zv + acc * acc);
    Cc[(size_t)row * 128 + t] = zv * inv;
    Ss[(size_t)row * 128 + t] = acc * inv;
}

// ---------- PLV Gram partials over 4 batches per block-z ----------
__global__ __launch_bounds__(256) void k_gram(const float* __restrict__ Cc, const float* __restrict__ Ss,
                                              float* __restrict__ Rp, float* __restrict__ Ip) {
    __shared__ float cis[16][132], sis[16][132], cjs[16][132], sjs[16][132];
    int tx = threadIdx.x, ty = threadIdx.y;
    int i0 = blockIdx.x * 16, j0 = blockIdx.y * 16, bz = blockIdx.z;
    int tid = ty * 16 + tx;
    int lr = tid >> 4;
    int lc = (tid & 15) * 8;
    float aR = 0.f, aI = 0.f;
    for (int b = bz * 4; b < bz * 4 + 4; ++b) {
        const float* pci = Cc + (size_t)b * 16384 + (size_t)(i0 + lr) * 128 + lc;
        const float* psi = Ss + (size_t)b * 16384 + (size_t)(i0 + lr) * 128 + lc;
        const float* pcj = Cc + (size_t)b * 16384 + (size_t)(j0 + lr) * 128 + lc;
        const float* psj = Ss + (size_t)b * 16384 + (size_t)(j0 + lr) * 128 + lc;
        __syncthreads();
        *(float4*)&cis[lr][lc] = *(const float4*)(pci);     *(float4*)&cis[lr][lc + 4] = *(const float4*)(pci + 4);
        *(float4*)&sis[lr][lc] = *(const float4*)(psi);     *(float4*)&sis[lr][lc + 4] = *(const float4*)(psi + 4);
        *(float4*)&cjs[lr][lc] = *(const float4*)(pcj);     *(float4*)&cjs[lr][lc + 4] = *(const float4*)(pcj + 4);
        *(float4*)&sjs[lr][lc] = *(const float4*)(psj);     *(float4*)&sjs[lr][lc + 4] = *(const float4*)(psj + 4);
        __syncthreads();
        #pragma unroll 8
        for (int tt = 0; tt < 128; ++tt) {
            float ci = cis[ty][tt], si = sis[ty][tt];
            float cj = cjs[tx][tt], sj = sjs[tx][tt];
            aR += ci * cj; aR += si * sj;
            aI += si * cj; aI -= ci * sj;
        }
    }
    Rp[(size_t)bz * 16384 + (size_t)(i0 + ty) * 128 + (j0 + tx)] = aR;
    Ip[(size_t)bz * 16384 + (size_t)(i0 + ty) * 128 + (j0 + tx)] = aI;
}

// ---------- reduce partials -> plv -> a;  also x = mean_b z ----------
__global__ __launch_bounds__(256) void k_plvx(const float* __restrict__ Rp, const float* __restrict__ Ip,
                                              const float* __restrict__ z,
                                              float* __restrict__ A, float* __restrict__ X) {
    int id = blockIdx.x * 256 + threadIdx.x;  // 16384
    float r = 0.f, im = 0.f;
    #pragma unroll
    for (int p = 0; p < 16; ++p) { r += Rp[p * 16384 + id]; im += Ip[p * 16384 + id]; }
    float plv = sqrtf(r * r + im * im) * (1.0f / 8192.0f);
    A[id] = (plv >= 0.5f) ? 1.0f : 0.0f;
    float s = 0.f;
    for (int b = 0; b < 64; ++b) s += z[(size_t)b * 16384 + id];
    X[id] = s * (1.0f / 64.0f);
}

// ---------- ax = a @ x ----------
__global__ __launch_bounds__(256) void k_ax(const float* __restrict__ A, const float* __restrict__ X,
                                            float* __restrict__ AX) {
    int id = blockIdx.x * 256 + threadIdx.x;  // 16384
    int i = id >> 7, t = id & 127;
    float s = 0.f;
    for (int j = 0; j < 128; ++j) s += A[i * 128 + j] * X[j * 128 + t];
    AX[id] = s;
}

// ---------- hg = relu(ax @ w_gae + b_gae) ----------
__global__ __launch_bounds__(256) void k_hg(const float* __restrict__ AX, const float* __restrict__ Wg,
                                            const float* __restrict__ bg, float* __restrict__ HG) {
    int id = blockIdx.x * 256 + threadIdx.x;  // 8192
    int i = id >> 6, h = id & 63;
    float s = bg[h];
    for (int t = 0; t < 128; ++t) s += AX[i * 128 + t] * Wg[t * 64 + h];
    HG[id] = fmaxf(s, 0.f);
}

// ---------- a_aug ----------
__global__ __launch_bounds__(256) void k_aaug(const float* __restrict__ HG, const float* __restrict__ A,
                                              const float* __restrict__ U, float* __restrict__ out) {
    int id = blockIdx.x * 256 + threadIdx.x;  // 16384
    int i = id >> 7, j = id & 127;
    float dot = 0.f;
    #pragma unroll 8
    for (int h = 0; h < 64; ++h) dot += HG[i * 64 + h] * HG[j * 64 + h];
    float p = 1.f / (1.f + expf(-dot));
    float e = 0.5f * p + 0.5f * A[id];
    float gmb = -logf(-logf(U[id]));
    float arg = (logf(e) - logf(1.f - e) + gmb) * 10.0f;
    out[AAUG_OFF + id] = 1.f / (1.f + expf(-arg));
}

extern "C" void kernel_launch(void* const* d_in, const int* in_sizes, int n_in,
                              void* d_out, int out_size, void* d_ws, size_t ws_size,
                              hipStream_t stream) {
    const float* z  = (const float*)d_in[0];
    const float* LF = (const float*)d_in[1];
    const float* U  = (const float*)d_in[2];
    const float* Wg = (const float*)d_in[3];
    const float* bg = (const float*)d_in[4];
    float* out = (float*)d_out;
    float* W = (float*)d_ws;

    float* dct  = W + OFF_DCT;
    float* dctT = W + OFF_DCTT;
    float* M1   = W + OFF_M1;
    float* MT   = W + OFF_MT;
    float* ZT   = W + OFF_ZT;
    float* Rp   = W + OFF_RP;
    float* Ip   = W + OFF_IP;
    float* A    = W + OFF_A;
    float* X    = W + OFF_X;
    float* AX   = W + OFF_AX;
    float* HG   = W + OFF_HG;
    float* Cc   = W + OFF_CC;
    float* Ss   = W + OFF_SS;

    k_dct<<<4104, 256, 0, stream>>>(dct, dctT);
    k_m1<<<64, 256, 0, stream>>>(dct, LF, M1, MT);
    k_m2<<<257, 256, 0, stream>>>(dctT, M1, MT);
    k_pad<<<128, 128, 0, stream>>>(MT);
    k_zt<<<dim3(256, 4), dim3(32, 8), 0, stream>>>(z, ZT);
    k_gemm<<<dim3(64, 21), 256, 0, stream>>>(MT, ZT, out);
    k_hilb<<<8192, 128, 0, stream>>>(z, Cc, Ss);   // overwrites dct/dctT region (done with them)
    k_gram<<<dim3(8, 8, 16), dim3(16, 16), 0, stream>>>(Cc, Ss, Rp, Ip);
    k_plvx<<<64, 256, 0, stream>>>(Rp, Ip, z, A, X);
    k_ax<<<64, 256, 0, stream>>>(A, X, AX);
    k_hg<<<32, 256, 0, stream>>>(AX, Wg, bg, HG);
    k_aaug<<<64, 256, 0, stream>>>(HG, A, U, out);
}

// Round 2
// 241.601 us; speedup vs baseline: 1.1754x; 1.1754x over previous
//
#include <hip/hip_runtime.h>

#define NV 2052
#define KD 512
#define RTOT 2564
#define RPAD 2688
#define JTOT 8192

// workspace float offsets
#define OFF_CC    0u
#define OFF_SS    1050624u
#define OFF_M1    2101248u
#define OFF_MT    2166784u
#define OFF_ZT    2510848u
#define OFF_RP    3559424u
#define OFF_IP    3821568u
#define OFF_A     4083712u
#define OFF_X     4100096u
#define OFF_AX    4116480u
#define OFF_HG    4132864u

#define SREC_OFF  4194304u
#define AAUG_OFF  21004288u

__device__ __forceinline__ float dct_val(int k, int v) {
    if (k == 0) return 1.0f / sqrtf(2052.0f);
    int m = (2 * v + 1) * k;
    int r = m % 8208;                       // exact arg reduction mod 2*pi
    float ang = (float)((double)r * (3.14159265358979323846 / 4104.0));
    return sqrtf(2.0f / 2052.0f) * cosf(ang);
}

// ---------- M1 = dct @ LF  (512 x 128), dct generated on the fly ----------
// grid 256 blocks: block b covers k rows {2b, 2b+1}; threads (kk=tid>>7, t=tid&127)
__global__ __launch_bounds__(256) void k_m1(const float* __restrict__ LF,
                                            float* __restrict__ M1, float* __restrict__ MT) {
    __shared__ float sd[2][128];
    const int tid = threadIdx.x;
    const int t = tid & 127;
    const int kk = tid >> 7;
    const int k0 = blockIdx.x * 2;
    const int myk = k0 + kk;
    float acc = 0.f;
    for (int v0 = 0; v0 < NV; v0 += 128) {
        int nv = min(128, NV - v0);
        __syncthreads();
        // stage dct[k0+kk][v0 + (tid&127)]
        if ((tid & 127) < nv) sd[kk][tid & 127] = dct_val(myk, v0 + (tid & 127));
        __syncthreads();
        const float* lf = LF + (size_t)v0 * 128 + t;
        int vi = 0;
        for (; vi + 4 <= nv; vi += 4) {
            float l0 = lf[(vi + 0) * 128];
            float l1 = lf[(vi + 1) * 128];
            float l2 = lf[(vi + 2) * 128];
            float l3 = lf[(vi + 3) * 128];
            acc += sd[kk][vi + 0] * l0;
            acc += sd[kk][vi + 1] * l1;
            acc += sd[kk][vi + 2] * l2;
            acc += sd[kk][vi + 3] * l3;
        }
        for (; vi < nv; ++vi) acc += sd[kk][vi] * lf[vi * 128];
    }
    M1[myk * 128 + t] = acc;
    MT[t * RPAD + myk] = acc;
}

// ---------- M2 = dctT @ M1 (2052 x 128), dct on the fly, written into MT cols 512.. ----------
// grid 1026 blocks: block b covers v rows {2b, 2b+1}; threads (vv=tid>>7, t=tid&127)
__global__ __launch_bounds__(256) void k_m2(const float* __restrict__ M1,
                                            float* __restrict__ MT) {
    __shared__ float sd[2][128];
    const int tid = threadIdx.x;
    const int t = tid & 127;
    const int vv = tid >> 7;
    const int v0 = blockIdx.x * 2;
    const int myv = v0 + vv;
    float acc = 0.f;
    for (int kc = 0; kc < KD; kc += 128) {
        __syncthreads();
        // stage dct[kc + (tid&127)][v0 + (tid>>7)]
        sd[tid >> 7][tid & 127] = dct_val(kc + (tid & 127), v0 + (tid >> 7));
        __syncthreads();
        const float* m1 = M1 + (size_t)kc * 128 + t;
        #pragma unroll 4
        for (int ki = 0; ki < 128; ++ki) acc += sd[vv][ki] * m1[ki * 128];
    }
    MT[t * RPAD + KD + myv] = acc;
}

// ---------- zero MT pad columns 2564..2687 ----------
__global__ void k_pad(float* __restrict__ MT) {
    int t = blockIdx.x;
    int c = threadIdx.x;
    if (c < RPAD - RTOT) MT[t * RPAD + RTOT + c] = 0.f;
}

// ---------- ZT[t][j] = zflat[j][t]  (transpose 8192x128 -> 128x8192) ----------
__global__ __launch_bounds__(256) void k_zt(const float* __restrict__ z, float* __restrict__ ZT) {
    __shared__ float tile[32][33];
    int j0 = blockIdx.x * 32, t0 = blockIdx.y * 32;
    int tx = threadIdx.x, ty = threadIdx.y;  // (32,8)
    #pragma unroll
    for (int k = 0; k < 4; ++k)
        tile[ty + 8 * k][tx] = z[(size_t)(j0 + ty + 8 * k) * 128 + t0 + tx];
    __syncthreads();
    #pragma unroll
    for (int k = 0; k < 4; ++k)
        ZT[(size_t)(t0 + ty + 8 * k) * JTOT + j0 + tx] = tile[tx][ty + 8 * k];
}

// ---------- big GEMM: C[r][j] = sum_t MT[t][r] * ZT[t][j], scattered to out ----------
__global__ __launch_bounds__(256) void k_gemm(const float* __restrict__ MT, const float* __restrict__ ZT,
                                              float* __restrict__ out) {
    __shared__ float As[32][132];
    __shared__ float Bs[32][132];
    const int tid = threadIdx.x;
    const int tx = tid & 15;
    const int ty = tid >> 4;
    const int j0 = blockIdx.x * 128;
    const int r0 = blockIdx.y * 128;
    const int lk = tid >> 3;          // 0..31
    const int lm = (tid & 7) * 16;    // 0..112
    float acc[8][8];
    #pragma unroll
    for (int i = 0; i < 8; ++i)
        #pragma unroll
        for (int j = 0; j < 8; ++j) acc[i][j] = 0.f;

    for (int kc = 0; kc < 128; kc += 32) {
        const float* pa = MT + (size_t)(kc + lk) * RPAD + r0 + lm;
        const float* pb = ZT + (size_t)(kc + lk) * JTOT + j0 + lm;
        float4 A0 = *(const float4*)(pa + 0);
        float4 A1 = *(const float4*)(pa + 4);
        float4 A2 = *(const float4*)(pa + 8);
        float4 A3 = *(const float4*)(pa + 12);
        float4 B0 = *(const float4*)(pb + 0);
        float4 B1 = *(const float4*)(pb + 4);
        float4 B2 = *(const float4*)(pb + 8);
        float4 B3 = *(const float4*)(pb + 12);
        __syncthreads();
        *(float4*)&As[lk][lm + 0] = A0;  *(float4*)&As[lk][lm + 4] = A1;
        *(float4*)&As[lk][lm + 8] = A2;  *(float4*)&As[lk][lm + 12] = A3;
        *(float4*)&Bs[lk][lm + 0] = B0;  *(float4*)&Bs[lk][lm + 4] = B1;
        *(float4*)&Bs[lk][lm + 8] = B2;  *(float4*)&Bs[lk][lm + 12] = B3;
        __syncthreads();
        #pragma unroll
        for (int kk = 0; kk < 32; ++kk) {
            float4 a0 = *(const float4*)&As[kk][ty * 8];
            float4 a1 = *(const float4*)&As[kk][ty * 8 + 4];
            float4 b0 = *(const float4*)&Bs[kk][tx * 8];
            float4 b1 = *(const float4*)&Bs[kk][tx * 8 + 4];
            float av[8] = {a0.x, a0.y, a0.z, a0.w, a1.x, a1.y, a1.z, a1.w};
            float bv[8] = {b0.x, b0.y, b0.z, b0.w, b1.x, b1.y, b1.z, b1.w};
            #pragma unroll
            for (int i = 0; i < 8; ++i)
                #pragma unroll
                for (int j = 0; j < 8; ++j)
                    acc[i][j] += av[i] * bv[j];
        }
    }
    const unsigned bb = (unsigned)blockIdx.x;  // batch index (j0>>7)
    #pragma unroll
    for (int im = 0; im < 8; ++im) {
        int r = r0 + ty * 8 + im;
        if (r < RTOT) {
            unsigned base;
            if (r < KD) base = bb * 65536u + (unsigned)r * 128u;
            else        base = SREC_OFF + bb * 262656u + (unsigned)(r - KD) * 128u;
            float4 w0 = make_float4(acc[im][0], acc[im][1], acc[im][2], acc[im][3]);
            float4 w1 = make_float4(acc[im][4], acc[im][5], acc[im][6], acc[im][7]);
            *(float4*)(out + base + tx * 8 + 0) = w0;
            *(float4*)(out + base + tx * 8 + 4) = w1;
        }
    }
}

// ---------- Hilbert (circular conv with cot kernel) -> cos/sin of phase ----------
__global__ __launch_bounds__(128) void k_hilb(const float* __restrict__ z,
                                              float* __restrict__ Cc, float* __restrict__ Ss) {
    __shared__ float zr[128];
    __shared__ float h[128];
    int row = blockIdx.x;
    int t = threadIdx.x;
    zr[t] = z[(size_t)row * 128 + t];
    float hv = 0.f;
    if (t & 1) {
        float ang = 3.14159265358979323846f * (float)t * (1.0f / 128.0f);
        hv = (cosf(ang) / sinf(ang)) * (1.0f / 64.0f);
    }
    h[t] = hv;
    __syncthreads();
    float acc = 0.f;
    #pragma unroll 8
    for (int i = 0; i < 64; ++i) {
        int d = 2 * i + 1;
        acc += h[d] * zr[(t - d) & 127];
    }
    float zv = zr[t];
    float inv = rsqrtf(zv * zv + acc * acc);
    Cc[(size_t)row * 128 + t] = zv * inv;
    Ss[(size_t)row * 128 + t] = acc * inv;
}

// ---------- PLV Gram partials over 4 batches per block-z ----------
__global__ __launch_bounds__(256) void k_gram(const float* __restrict__ Cc, const float* __restrict__ Ss,
                                              float* __restrict__ Rp, float* __restrict__ Ip) {
    __shared__ float cis[16][132], sis[16][132], cjs[16][132], sjs[16][132];
    int tx = threadIdx.x, ty = threadIdx.y;
    int i0 = blockIdx.x * 16, j0 = blockIdx.y * 16, bz = blockIdx.z;
    int tid = ty * 16 + tx;
    int lr = tid >> 4;
    int lc = (tid & 15) * 8;
    float aR = 0.f, aI = 0.f;
    for (int b = bz * 4; b < bz * 4 + 4; ++b) {
        const float* pci = Cc + (size_t)b * 16384 + (size_t)(i0 + lr) * 128 + lc;
        const float* psi = Ss + (size_t)b * 16384 + (size_t)(i0 + lr) * 128 + lc;
        const float* pcj = Cc + (size_t)b * 16384 + (size_t)(j0 + lr) * 128 + lc;
        const float* psj = Ss + (size_t)b * 16384 + (size_t)(j0 + lr) * 128 + lc;
        __syncthreads();
        *(float4*)&cis[lr][lc] = *(const float4*)(pci);     *(float4*)&cis[lr][lc + 4] = *(const float4*)(pci + 4);
        *(float4*)&sis[lr][lc] = *(const float4*)(psi);     *(float4*)&sis[lr][lc + 4] = *(const float4*)(psi + 4);
        *(float4*)&cjs[lr][lc] = *(const float4*)(pcj);     *(float4*)&cjs[lr][lc + 4] = *(const float4*)(pcj + 4);
        *(float4*)&sjs[lr][lc] = *(const float4*)(psj);     *(float4*)&sjs[lr][lc + 4] = *(const float4*)(psj + 4);
        __syncthreads();
        #pragma unroll 8
        for (int tt = 0; tt < 128; ++tt) {
            float ci = cis[ty][tt], si = sis[ty][tt];
            float cj = cjs[tx][tt], sj = sjs[tx][tt];
            aR += ci * cj; aR += si * sj;
            aI += si * cj; aI -= ci * sj;
        }
    }
    Rp[(size_t)bz * 16384 + (size_t)(i0 + ty) * 128 + (j0 + tx)] = aR;
    Ip[(size_t)bz * 16384 + (size_t)(i0 + ty) * 128 + (j0 + tx)] = aI;
}

// ---------- reduce partials -> plv -> a;  also x = mean_b z ----------
__global__ __launch_bounds__(256) void k_plvx(const float* __restrict__ Rp, const float* __restrict__ Ip,
                                              const float* __restrict__ z,
                                              float* __restrict__ A, float* __restrict__ X) {
    int id = blockIdx.x * 256 + threadIdx.x;  // 16384
    float r = 0.f, im = 0.f;
    #pragma unroll
    for (int p = 0; p < 16; ++p) { r += Rp[p * 16384 + id]; im += Ip[p * 16384 + id]; }
    float plv = sqrtf(r * r + im * im) * (1.0f / 8192.0f);
    A[id] = (plv >= 0.5f) ? 1.0f : 0.0f;
    float s = 0.f;
    for (int b = 0; b < 64; ++b) s += z[(size_t)b * 16384 + id];
    X[id] = s * (1.0f / 64.0f);
}

// ---------- ax = a @ x ----------
__global__ __launch_bounds__(256) void k_ax(const float* __restrict__ A, const float* __restrict__ X,
                                            float* __restrict__ AX) {
    int id = blockIdx.x * 256 + threadIdx.x;  // 16384
    int i = id >> 7, t = id & 127;
    float s = 0.f;
    for (int j = 0; j < 128; ++j) s += A[i * 128 + j] * X[j * 128 + t];
    AX[id] = s;
}

// ---------- hg = relu(ax @ w_gae + b_gae) ----------
__global__ __launch_bounds__(256) void k_hg(const float* __restrict__ AX, const float* __restrict__ Wg,
                                            const float* __restrict__ bg, float* __restrict__ HG) {
    int id = blockIdx.x * 256 + threadIdx.x;  // 8192
    int i = id >> 6, h = id & 63;
    float s = bg[h];
    for (int t = 0; t < 128; ++t) s += AX[i * 128 + t] * Wg[t * 64 + h];
    HG[id] = fmaxf(s, 0.f);
}

// ---------- a_aug ----------
__global__ __launch_bounds__(256) void k_aaug(const float* __restrict__ HG, const float* __restrict__ A,
                                              const float* __restrict__ U, float* __restrict__ out) {
    int id = blockIdx.x * 256 + threadIdx.x;  // 16384
    int i = id >> 7, j = id & 127;
    float dot = 0.f;
    #pragma unroll 8
    for (int h = 0; h < 64; ++h) dot += HG[i * 64 + h] * HG[j * 64 + h];
    float p = 1.f / (1.f + expf(-dot));
    float e = 0.5f * p + 0.5f * A[id];
    float gmb = -logf(-logf(U[id]));
    float arg = (logf(e) - logf(1.f - e) + gmb) * 10.0f;
    out[AAUG_OFF + id] = 1.f / (1.f + expf(-arg));
}

extern "C" void kernel_launch(void* const* d_in, const int* in_sizes, int n_in,
                              void* d_out, int out_size, void* d_ws, size_t ws_size,
                              hipStream_t stream) {
    const float* z  = (const float*)d_in[0];
    const float* LF = (const float*)d_in[1];
    const float* U  = (const float*)d_in[2];
    const float* Wg = (const float*)d_in[3];
    const float* bg = (const float*)d_in[4];
    float* out = (float*)d_out;
    float* W = (float*)d_ws;

    float* Cc   = W + OFF_CC;
    float* Ss   = W + OFF_SS;
    float* M1   = W + OFF_M1;
    float* MT   = W + OFF_MT;
    float* ZT   = W + OFF_ZT;
    float* Rp   = W + OFF_RP;
    float* Ip   = W + OFF_IP;
    float* A    = W + OFF_A;
    float* X    = W + OFF_X;
    float* AX   = W + OFF_AX;
    float* HG   = W + OFF_HG;

    k_m1<<<256, 256, 0, stream>>>(LF, M1, MT);
    k_m2<<<1026, 256, 0, stream>>>(M1, MT);
    k_pad<<<128, 128, 0, stream>>>(MT);
    k_zt<<<dim3(256, 4), dim3(32, 8), 0, stream>>>(z, ZT);
    k_gemm<<<dim3(64, 21), 256, 0, stream>>>(MT, ZT, out);
    k_hilb<<<8192, 128, 0, stream>>>(z, Cc, Ss);
    k_gram<<<dim3(8, 8, 16), dim3(16, 16), 0, stream>>>(Cc, Ss, Rp, Ip);
    k_plvx<<<64, 256, 0, stream>>>(Rp, Ip, z, A, X);
    k_ax<<<64, 256, 0, stream>>>(A, X, AX);
    k_hg<<<32, 256, 0, stream>>>(AX, Wg, bg, HG);
    k_aaug<<<64, 256, 0, stream>>>(HG, A, U, out);
}

// Round 3
// 150.906 us; speedup vs baseline: 1.8818x; 1.6010x over previous
//
#include <hip/hip_runtime.h>

#define NV 2052
#define KD 512
#define RTOT 2564
#define MPAD 2688
#define KTOT 384
#define JTOT 8192

typedef __attribute__((ext_vector_type(8))) short short8v;
typedef __attribute__((ext_vector_type(4))) float f32x4;
typedef unsigned short ushort_t;

// ws float offsets
#define OFF_AF   0u
#define OFF_ABF  344064u
#define OFF_BBF  860160u
#define OFF_SCR  2433024u
#define OFF_RP   3481600u
#define OFF_IP   3743744u
#define OFF_A    4005888u
#define OFF_X    4022272u
#define OFF_AX   4038656u
#define OFF_HG   4055040u

#define SREC_OFF 4194304u
#define AAUG_OFF 21004288u

#define GLOAD16(g, l) __builtin_amdgcn_global_load_lds( \
    (const __attribute__((address_space(1))) unsigned int*)(g), \
    (__attribute__((address_space(3))) unsigned int*)(l), 16, 0, 0)

__device__ __forceinline__ float dct_val(int k, int v) {
    if (k == 0) return 1.0f / sqrtf(2052.0f);
    int m = (2 * v + 1) * k;
    int r = m % 8208;                       // exact arg reduction mod 2*pi
    float ang = (float)((double)r * (3.14159265358979323846 / 4104.0));
    return sqrtf(2.0f / 2052.0f) * cosf(ang);
}

// ---------- M1 partials: grid (64 k-groups, 16 v-chunks) ----------
// block: 8 k-rows x one v-chunk (128, last=132). thread: 4 k-rows, 1 col.
__global__ __launch_bounds__(256) void k_m1(const float* __restrict__ LF, float* __restrict__ Pm1) {
    __shared__ float sd[8][132];
    const int tid = threadIdx.x;
    const int t = tid & 127;
    const int kk = tid >> 7;       // 0/1
    const int k0 = blockIdx.x * 8;
    const int vch = blockIdx.y;
    const int v0 = vch * 128;
    const int nv = (vch == 15) ? 132 : 128;
    for (int p = tid; p < 1056; p += 256) {
        int rr = p / 132, cc = p - rr * 132;
        sd[rr][cc] = dct_val(k0 + rr, v0 + cc);
    }
    __syncthreads();
    const float* lf = LF + (size_t)v0 * 128 + t;
    float a0 = 0.f, a1 = 0.f, a2 = 0.f, a3 = 0.f;
    int vi = 0;
    for (; vi + 2 <= nv; vi += 2) {
        float l0 = lf[vi * 128], l1 = lf[vi * 128 + 128];
        a0 += sd[kk + 0][vi] * l0; a1 += sd[kk + 2][vi] * l0;
        a2 += sd[kk + 4][vi] * l0; a3 += sd[kk + 6][vi] * l0;
        a0 += sd[kk + 0][vi + 1] * l1; a1 += sd[kk + 2][vi + 1] * l1;
        a2 += sd[kk + 4][vi + 1] * l1; a3 += sd[kk + 6][vi + 1] * l1;
    }
    float* P = Pm1 + (size_t)vch * 65536;
    P[(k0 + kk + 0) * 128 + t] = a0;
    P[(k0 + kk + 2) * 128 + t] = a1;
    P[(k0 + kk + 4) * 128 + t] = a2;
    P[(k0 + kk + 6) * 128 + t] = a3;
}

// ---------- reduce 16 partials -> AF rows 0..511 (M1[k][t]) ----------
__global__ __launch_bounds__(256) void k_m1red(const float* __restrict__ Pm1, float* __restrict__ AF) {
    int id = blockIdx.x * 256 + threadIdx.x;  // 65536
    float s = 0.f;
    #pragma unroll
    for (int p = 0; p < 16; ++p) s += Pm1[p * 65536 + id];
    AF[id] = s;
}

// ---------- M2 = dctT @ M1 -> AF rows 512..2563 ([v][t]) ----------
__global__ __launch_bounds__(256) void k_m2(const float* __restrict__ M1, float* __restrict__ AF2) {
    __shared__ float sd[2][128];
    const int tid = threadIdx.x;
    const int t = tid & 127;
    const int vv = tid >> 7;
    const int myv = blockIdx.x * 2 + vv;
    float a0 = 0.f, a1 = 0.f, a2 = 0.f, a3 = 0.f;
    for (int kc = 0; kc < KD; kc += 128) {
        __syncthreads();
        sd[vv][t] = dct_val(kc + t, myv);
        __syncthreads();
        const float* m1 = M1 + (size_t)kc * 128 + t;
        #pragma unroll 8
        for (int ki = 0; ki < 32; ++ki) {
            a0 += sd[vv][ki +  0] * m1[(ki +  0) * 128];
            a1 += sd[vv][ki + 32] * m1[(ki + 32) * 128];
            a2 += sd[vv][ki + 64] * m1[(ki + 64) * 128];
            a3 += sd[vv][ki + 96] * m1[(ki + 96) * 128];
        }
    }
    AF2[(size_t)myv * 128 + t] = (a0 + a1) + (a2 + a3);
}

// ---------- split fp32 -> (hi, hi, lo) bf16 rows, K'=384 ----------
__device__ __forceinline__ void bf16split(float x, ushort_t& hi, ushort_t& lo) {
    unsigned xb = __float_as_uint(x);
    hi = (ushort_t)(xb >> 16);
    float r = x - __uint_as_float((unsigned)hi << 16);
    lo = (ushort_t)(__float_as_uint(r) >> 16);
}

__global__ __launch_bounds__(256) void k_convA(const float* __restrict__ AF, ushort_t* __restrict__ Abf) {
    int rid = blockIdx.x * 2 + (threadIdx.x >> 7);
    int t = threadIdx.x & 127;
    float x = (rid < RTOT) ? AF[(size_t)rid * 128 + t] : 0.f;
    ushort_t hi, lo; bf16split(x, hi, lo);
    ushort_t* row = Abf + (size_t)rid * KTOT;
    row[t] = hi; row[128 + t] = hi; row[256 + t] = lo;
}

__global__ __launch_bounds__(256) void k_convB(const float* __restrict__ z, ushort_t* __restrict__ Bbf) {
    int rid = blockIdx.x * 2 + (threadIdx.x >> 7);
    int t = threadIdx.x & 127;
    float x = z[(size_t)rid * 128 + t];
    ushort_t hi, lo; bf16split(x, hi, lo);
    ushort_t* row = Bbf + (size_t)rid * KTOT;
    row[t] = hi; row[128 + t] = lo; row[256 + t] = hi;
}

// ---------- MFMA GEMM: C[r][j] = sum_k' A'[r][k'] B'[j][k'], K'=384 ----------
__global__ __launch_bounds__(256) void k_gemm(const ushort_t* __restrict__ Abf, const ushort_t* __restrict__ Bbf,
                                              float* __restrict__ out) {
    __shared__ ushort_t Al[128 * 64];   // [m][k] 128 rows x 64 k (128B rows)
    __shared__ ushort_t Bl[128 * 64];
    const int tid = threadIdx.x;
    const int wave = tid >> 6;
    const int lane = tid & 63;
    const int j0 = blockIdx.x * 128;
    const int r0 = blockIdx.y * 128;
    const int wr = wave >> 1, wc = wave & 1;
    const int l15 = lane & 15;
    const int lhi = lane >> 4;

    f32x4 acc[4][4];
    #pragma unroll
    for (int i = 0; i < 4; ++i)
        #pragma unroll
        for (int j = 0; j < 4; ++j)
            acc[i][j] = (f32x4){0.f, 0.f, 0.f, 0.f};

    for (int kc = 0; kc < KTOT; kc += 64) {
        __syncthreads();
        #pragma unroll
        for (int i = 0; i < 4; ++i) {
            int elt = (wave * 4 + i) * 64 + lane;   // 0..1023 16B-chunks
            int m = elt >> 3;
            int kb = (elt & 7) * 8;                 // ushort offset in row
            const ushort_t* ga = Abf + (size_t)(r0 + m) * KTOT + kc + kb;
            const ushort_t* gb = Bbf + (size_t)(j0 + m) * KTOT + kc + kb;
            GLOAD16(ga, &Al[(wave * 4 + i) * 512]);
            GLOAD16(gb, &Bl[(wave * 4 + i) * 512]);
        }
        asm volatile("s_waitcnt vmcnt(0)" ::: "memory");
        __syncthreads();
        #pragma unroll
        for (int kk = 0; kk < 2; ++kk) {
            short8v av[4], bv[4];
            #pragma unroll
            for (int mi = 0; mi < 4; ++mi) {
                int m = wr * 64 + mi * 16 + l15;
                av[mi] = *(const short8v*)&Al[m * 64 + kk * 32 + lhi * 8];
            }
            #pragma unroll
            for (int ni = 0; ni < 4; ++ni) {
                int n = wc * 64 + ni * 16 + l15;
                bv[ni] = *(const short8v*)&Bl[n * 64 + kk * 32 + lhi * 8];
            }
            #pragma unroll
            for (int mi = 0; mi < 4; ++mi)
                #pragma unroll
                for (int ni = 0; ni < 4; ++ni)
                    acc[mi][ni] = __builtin_amdgcn_mfma_f32_16x16x32_bf16(av[mi], bv[ni], acc[mi][ni], 0, 0, 0);
        }
    }

    const unsigned bb = (unsigned)blockIdx.x;
    #pragma unroll
    for (int mi = 0; mi < 4; ++mi) {
        int rbase = r0 + wr * 64 + mi * 16 + lhi * 4;
        #pragma unroll
        for (int reg = 0; reg < 4; ++reg) {
            int r = rbase + reg;
            unsigned base; bool ok = true;
            if (r < KD) base = bb * 65536u + (unsigned)r * 128u;
            else if (r < RTOT) base = SREC_OFF + bb * 262656u + (unsigned)(r - KD) * 128u;
            else ok = false;
            if (ok) {
                #pragma unroll
                for (int ni = 0; ni < 4; ++ni) {
                    int n = wc * 64 + ni * 16 + l15;
                    out[base + n] = acc[mi][ni][reg];
                }
            }
        }
    }
}

// ---------- Hilbert (circular conv with cot kernel) -> cos/sin of phase ----------
__global__ __launch_bounds__(128) void k_hilb(const float* __restrict__ z,
                                              float* __restrict__ Cc, float* __restrict__ Ss) {
    __shared__ float zr[128];
    __shared__ float h[128];
    int row = blockIdx.x;
    int t = threadIdx.x;
    zr[t] = z[(size_t)row * 128 + t];
    float hv = 0.f;
    if (t & 1) {
        float ang = 3.14159265358979323846f * (float)t * (1.0f / 128.0f);
        hv = (cosf(ang) / sinf(ang)) * (1.0f / 64.0f);
    }
    h[t] = hv;
    __syncthreads();
    float acc = 0.f;
    #pragma unroll 8
    for (int i = 0; i < 64; ++i) {
        int d = 2 * i + 1;
        acc += h[d] * zr[(t - d) & 127];
    }
    float zv = zr[t];
    float inv = rsqrtf(zv * zv + acc * acc);
    Cc[(size_t)row * 128 + t] = zv * inv;
    Ss[(size_t)row * 128 + t] = acc * inv;
}

// ---------- PLV Gram partials over 4 batches per block-z ----------
__global__ __launch_bounds__(256) void k_gram(const float* __restrict__ Cc, const float* __restrict__ Ss,
                                              float* __restrict__ Rp, float* __restrict__ Ip) {
    __shared__ float cis[16][132], sis[16][132], cjs[16][132], sjs[16][132];
    int tx = threadIdx.x, ty = threadIdx.y;
    int i0 = blockIdx.x * 16, j0 = blockIdx.y * 16, bz = blockIdx.z;
    int tid = ty * 16 + tx;
    int lr = tid >> 4;
    int lc = (tid & 15) * 8;
    float aR = 0.f, aI = 0.f;
    for (int b = bz * 4; b < bz * 4 + 4; ++b) {
        const float* pci = Cc + (size_t)b * 16384 + (size_t)(i0 + lr) * 128 + lc;
        const float* psi = Ss + (size_t)b * 16384 + (size_t)(i0 + lr) * 128 + lc;
        const float* pcj = Cc + (size_t)b * 16384 + (size_t)(j0 + lr) * 128 + lc;
        const float* psj = Ss + (size_t)b * 16384 + (size_t)(j0 + lr) * 128 + lc;
        __syncthreads();
        *(float4*)&cis[lr][lc] = *(const float4*)(pci);     *(float4*)&cis[lr][lc + 4] = *(const float4*)(pci + 4);
        *(float4*)&sis[lr][lc] = *(const float4*)(psi);     *(float4*)&sis[lr][lc + 4] = *(const float4*)(psi + 4);
        *(float4*)&cjs[lr][lc] = *(const float4*)(pcj);     *(float4*)&cjs[lr][lc + 4] = *(const float4*)(pcj + 4);
        *(float4*)&sjs[lr][lc] = *(const float4*)(psj);     *(float4*)&sjs[lr][lc + 4] = *(const float4*)(psj + 4);
        __syncthreads();
        #pragma unroll 8
        for (int tt = 0; tt < 128; ++tt) {
            float ci = cis[ty][tt], si = sis[ty][tt];
            float cj = cjs[tx][tt], sj = sjs[tx][tt];
            aR += ci * cj; aR += si * sj;
            aI += si * cj; aI -= ci * sj;
        }
    }
    Rp[(size_t)bz * 16384 + (size_t)(i0 + ty) * 128 + (j0 + tx)] = aR;
    Ip[(size_t)bz * 16384 + (size_t)(i0 + ty) * 128 + (j0 + tx)] = aI;
}

// ---------- reduce partials -> plv -> a;  also x = mean_b z ----------
__global__ __launch_bounds__(256) void k_plvx(const float* __restrict__ Rp, const float* __restrict__ Ip,
                                              const float* __restrict__ z,
                                              float* __restrict__ A, float* __restrict__ X) {
    int id = blockIdx.x * 256 + threadIdx.x;  // 16384
    float r = 0.f, im = 0.f;
    #pragma unroll
    for (int p = 0; p < 16; ++p) { r += Rp[p * 16384 + id]; im += Ip[p * 16384 + id]; }
    float plv = sqrtf(r * r + im * im) * (1.0f / 8192.0f);
    A[id] = (plv >= 0.5f) ? 1.0f : 0.0f;
    float s = 0.f;
    for (int b = 0; b < 64; ++b) s += z[(size_t)b * 16384 + id];
    X[id] = s * (1.0f / 64.0f);
}

// ---------- ax = a @ x ----------
__global__ __launch_bounds__(256) void k_ax(const float* __restrict__ A, const float* __restrict__ X,
                                            float* __restrict__ AX) {
    int id = blockIdx.x * 256 + threadIdx.x;  // 16384
    int i = id >> 7, t = id & 127;
    float s = 0.f;
    for (int j = 0; j < 128; ++j) s += A[i * 128 + j] * X[j * 128 + t];
    AX[id] = s;
}

// ---------- hg = relu(ax @ w_gae + b_gae) ----------
__global__ __launch_bounds__(256) void k_hg(const float* __restrict__ AX, const float* __restrict__ Wg,
                                            const float* __restrict__ bg, float* __restrict__ HG) {
    int id = blockIdx.x * 256 + threadIdx.x;  // 8192
    int i = id >> 6, h = id & 63;
    float s = bg[h];
    for (int t = 0; t < 128; ++t) s += AX[i * 128 + t] * Wg[t * 64 + h];
    HG[id] = fmaxf(s, 0.f);
}

// ---------- a_aug ----------
__global__ __launch_bounds__(256) void k_aaug(const float* __restrict__ HG, const float* __restrict__ A,
                                              const float* __restrict__ U, float* __restrict__ out) {
    int id = blockIdx.x * 256 + threadIdx.x;  // 16384
    int i = id >> 7, j = id & 127;
    float dot = 0.f;
    #pragma unroll 8
    for (int h = 0; h < 64; ++h) dot += HG[i * 64 + h] * HG[j * 64 + h];
    float p = 1.f / (1.f + expf(-dot));
    float e = 0.5f * p + 0.5f * A[id];
    float gmb = -logf(-logf(U[id]));
    float arg = (logf(e) - logf(1.f - e) + gmb) * 10.0f;
    out[AAUG_OFF + id] = 1.f / (1.f + expf(-arg));
}

extern "C" void kernel_launch(void* const* d_in, const int* in_sizes, int n_in,
                              void* d_out, int out_size, void* d_ws, size_t ws_size,
                              hipStream_t stream) {
    const float* z  = (const float*)d_in[0];
    const float* LF = (const float*)d_in[1];
    const float* U  = (const float*)d_in[2];
    const float* Wg = (const float*)d_in[3];
    const float* bg = (const float*)d_in[4];
    float* out = (float*)d_out;
    float* W = (float*)d_ws;

    float* AF  = W + OFF_AF;                    // [2688?][128] fp32 (rows 0..2563 valid)
    ushort_t* Abf = (ushort_t*)(W + OFF_ABF);   // [2688][384] bf16
    ushort_t* Bbf = (ushort_t*)(W + OFF_BBF);   // [8192][384] bf16
    float* SCR = W + OFF_SCR;                   // Pm1 partials, later Ss
    float* Rp  = W + OFF_RP;
    float* Ip  = W + OFF_IP;
    float* A   = W + OFF_A;
    float* X   = W + OFF_X;
    float* AX  = W + OFF_AX;
    float* HG  = W + OFF_HG;
    float* Cc  = (float*)(W + OFF_BBF);         // reuse Bbf region after gemm
    float* Ss  = SCR;                           // reuse Pm1 region after m1red

    k_m1   <<<dim3(64, 16), 256, 0, stream>>>(LF, SCR);
    k_m1red<<<256, 256, 0, stream>>>(SCR, AF);
    k_m2   <<<1026, 256, 0, stream>>>(AF, AF + (size_t)KD * 128);
    k_convA<<<1344, 256, 0, stream>>>(AF, Abf);
    k_convB<<<4096, 256, 0, stream>>>(z, Bbf);
    k_gemm <<<dim3(64, 21), 256, 0, stream>>>(Abf, Bbf, out);
    k_hilb <<<8192, 128, 0, stream>>>(z, Cc, Ss);
    k_gram <<<dim3(8, 8, 16), dim3(16, 16), 0, stream>>>(Cc, Ss, Rp, Ip);
    k_plvx <<<64, 256, 0, stream>>>(Rp, Ip, z, A, X);
    k_ax   <<<64, 256, 0, stream>>>(A, X, AX);
    k_hg   <<<32, 256, 0, stream>>>(AX, Wg, bg, HG);
    k_aaug <<<64, 256, 0, stream>>>(HG, A, U, out);
}

// Round 4
// 137.713 us; speedup vs baseline: 2.0621x; 1.0958x over previous
//
#include <hip/hip_runtime.h>

#define NV 2052
#define KD 512
#define RTOT 2564
#define KTOT 384
#define JTOT 8192

typedef __attribute__((ext_vector_type(8))) short short8v;
typedef __attribute__((ext_vector_type(4))) float f32x4;
typedef unsigned short ushort_t;

// ws float offsets
#define OFF_AF   0u          // fp32 M1 rows [512][128]
#define OFF_ABF  65536u      // bf16 A' [2688][384]
#define OFF_BBF  581632u     // bf16 B' [8192][384]
#define OFF_YBF  2154496u    // bf16 Y  [256][8192]  (also Pm1 partials before hilb)
#define OFF_PG   3203072u    // fp32 Gram partials [32][4][128][128]
#define OFF_A    5300224u
#define OFF_X    5316608u
#define OFF_AX   5332992u
#define OFF_HG   5349376u

#define SREC_OFF 4194304u
#define AAUG_OFF 21004288u

#define GLOAD16(g, l) __builtin_amdgcn_global_load_lds( \
    (const __attribute__((address_space(1))) unsigned int*)(g), \
    (__attribute__((address_space(3))) unsigned int*)(l), 16, 0, 0)

__device__ __forceinline__ float dct_val(int k, int v) {
    if (k == 0) return 1.0f / sqrtf(2052.0f);
    int m = (2 * v + 1) * k;
    int r = m % 8208;                       // exact arg reduction mod 2*pi
    float ang = (float)((double)r * (3.14159265358979323846 / 4104.0));
    return sqrtf(2.0f / 2052.0f) * cosf(ang);
}

__device__ __forceinline__ void bf16split(float x, ushort_t& hi, ushort_t& lo) {
    unsigned xb = __float_as_uint(x);
    hi = (ushort_t)(xb >> 16);
    float r = x - __uint_as_float((unsigned)hi << 16);
    lo = (ushort_t)(__float_as_uint(r) >> 16);
}

__device__ __forceinline__ ushort_t bf16rn(float x) {
    unsigned xb = __float_as_uint(x);
    return (ushort_t)((xb + 0x7fffu + ((xb >> 16) & 1u)) >> 16);
}

// ---------- M1 partials: grid (64 k-groups, 16 v-chunks) ----------
__global__ __launch_bounds__(256) void k_m1(const float* __restrict__ LF, float* __restrict__ Pm1) {
    __shared__ float sd[8][132];
    const int tid = threadIdx.x;
    const int t = tid & 127;
    const int kk = tid >> 7;       // 0/1
    const int k0 = blockIdx.x * 8;
    const int vch = blockIdx.y;
    const int v0 = vch * 128;
    const int nv = (vch == 15) ? 132 : 128;
    for (int p = tid; p < 1056; p += 256) {
        int rr = p / 132, cc = p - rr * 132;
        sd[rr][cc] = dct_val(k0 + rr, v0 + cc);
    }
    __syncthreads();
    const float* lf = LF + (size_t)v0 * 128 + t;
    float a0 = 0.f, a1 = 0.f, a2 = 0.f, a3 = 0.f;
    int vi = 0;
    for (; vi + 2 <= nv; vi += 2) {
        float l0 = lf[vi * 128], l1 = lf[vi * 128 + 128];
        a0 += sd[kk + 0][vi] * l0; a1 += sd[kk + 2][vi] * l0;
        a2 += sd[kk + 4][vi] * l0; a3 += sd[kk + 6][vi] * l0;
        a0 += sd[kk + 0][vi + 1] * l1; a1 += sd[kk + 2][vi + 1] * l1;
        a2 += sd[kk + 4][vi + 1] * l1; a3 += sd[kk + 6][vi + 1] * l1;
    }
    float* P = Pm1 + (size_t)vch * 65536;
    P[(k0 + kk + 0) * 128 + t] = a0;
    P[(k0 + kk + 2) * 128 + t] = a1;
    P[(k0 + kk + 4) * 128 + t] = a2;
    P[(k0 + kk + 6) * 128 + t] = a3;
}

// ---------- reduce partials -> AF fp32 rows 0..511 AND Abf bf16 rows ----------
__global__ __launch_bounds__(256) void k_m1red(const float* __restrict__ Pm1, float* __restrict__ AF,
                                               ushort_t* __restrict__ Abf) {
    int id = blockIdx.x * 256 + threadIdx.x;  // 65536
    float s = 0.f;
    #pragma unroll
    for (int p = 0; p < 16; ++p) s += Pm1[p * 65536 + id];
    AF[id] = s;
    int rid = id >> 7, t = id & 127;
    ushort_t hi, lo; bf16split(s, hi, lo);
    ushort_t* row = Abf + (size_t)rid * KTOT;
    row[t] = hi; row[128 + t] = hi; row[256 + t] = lo;
}

// ---------- M2 = dctT @ M1 -> Abf rows 512..2563 directly ----------
__global__ __launch_bounds__(256) void k_m2(const float* __restrict__ M1, ushort_t* __restrict__ Abf) {
    __shared__ float sd[2][128];
    const int tid = threadIdx.x;
    const int t = tid & 127;
    const int vv = tid >> 7;
    const int myv = blockIdx.x * 2 + vv;
    float a0 = 0.f, a1 = 0.f, a2 = 0.f, a3 = 0.f;
    for (int kc = 0; kc < KD; kc += 128) {
        __syncthreads();
        sd[vv][t] = dct_val(kc + t, myv);
        __syncthreads();
        const float* m1 = M1 + (size_t)kc * 128 + t;
        #pragma unroll 8
        for (int ki = 0; ki < 32; ++ki) {
            a0 += sd[vv][ki +  0] * m1[(ki +  0) * 128];
            a1 += sd[vv][ki + 32] * m1[(ki + 32) * 128];
            a2 += sd[vv][ki + 64] * m1[(ki + 64) * 128];
            a3 += sd[vv][ki + 96] * m1[(ki + 96) * 128];
        }
    }
    float s = (a0 + a1) + (a2 + a3);
    ushort_t hi, lo; bf16split(s, hi, lo);
    ushort_t* row = Abf + (size_t)(KD + myv) * KTOT;
    row[t] = hi; row[128 + t] = hi; row[256 + t] = lo;
}

// ---------- Hilbert: emit Y bf16 (cos rows 0..127, sin rows 128..255, col b*128+t)
//            AND B' bf16 triple rows for the big GEMM ----------
__global__ __launch_bounds__(256) void k_hilb(const float* __restrict__ z,
                                              ushort_t* __restrict__ Ybf, ushort_t* __restrict__ Bbf) {
    __shared__ float zr[2][128];
    __shared__ float h[128];
    const int tid = threadIdx.x;
    const int t = tid & 127;
    const int rr = tid >> 7;
    const int rid = blockIdx.x * 2 + rr;   // b*128+i
    const int b = rid >> 7, i = rid & 127;
    zr[rr][t] = z[(size_t)rid * 128 + t];
    if (tid < 128) {
        float hv = 0.f;
        if (t & 1) {
            float ang = 3.14159265358979323846f * (float)t * (1.0f / 128.0f);
            hv = (cosf(ang) / sinf(ang)) * (1.0f / 64.0f);
        }
        h[t] = hv;
    }
    __syncthreads();
    float acc = 0.f;
    #pragma unroll 8
    for (int q = 0; q < 64; ++q) {
        int d = 2 * q + 1;
        acc += h[d] * zr[rr][(t - d) & 127];
    }
    float zv = zr[rr][t];
    float inv = rsqrtf(zv * zv + acc * acc);
    Ybf[(size_t)i * JTOT + b * 128 + t] = bf16rn(zv * inv);
    Ybf[(size_t)(128 + i) * JTOT + b * 128 + t] = bf16rn(acc * inv);
    ushort_t hi, lo; bf16split(zv, hi, lo);
    ushort_t* row = Bbf + (size_t)rid * KTOT;
    row[t] = hi; row[128 + t] = lo; row[256 + t] = hi;
}

// ---------- MFMA GEMM: C[r][j] = sum_k' A'[r][k'] B'[j][k'], K'=384 ----------
__global__ __launch_bounds__(256) void k_gemm(const ushort_t* __restrict__ Abf, const ushort_t* __restrict__ Bbf,
                                              float* __restrict__ out) {
    __shared__ float SMf[8704];            // 34816 B: Al+Bl (32KB) overlay, epilogue Ls [128][68]
    ushort_t* Al = (ushort_t*)SMf;         // [128*64]
    ushort_t* Bl = Al + 8192;
    const int tid = threadIdx.x;
    const int wave = tid >> 6;
    const int lane = tid & 63;
    const int j0 = blockIdx.x * 128;
    const int r0 = blockIdx.y * 128;
    const int wr = wave >> 1, wc = wave & 1;
    const int l15 = lane & 15;
    const int lhi = lane >> 4;

    f32x4 acc[4][4];
    #pragma unroll
    for (int i = 0; i < 4; ++i)
        #pragma unroll
        for (int j = 0; j < 4; ++j)
            acc[i][j] = (f32x4){0.f, 0.f, 0.f, 0.f};

    for (int kc = 0; kc < KTOT; kc += 64) {
        __syncthreads();
        #pragma unroll
        for (int i = 0; i < 4; ++i) {
            int elt = (wave * 4 + i) * 64 + lane;   // 0..1023 16B chunks
            int m = elt >> 3;
            int kb = (elt & 7) * 8;
            const ushort_t* ga = Abf + (size_t)(r0 + m) * KTOT + kc + kb;
            const ushort_t* gb = Bbf + (size_t)(j0 + m) * KTOT + kc + kb;
            GLOAD16(ga, &Al[(wave * 4 + i) * 512]);
            GLOAD16(gb, &Bl[(wave * 4 + i) * 512]);
        }
        asm volatile("s_waitcnt vmcnt(0)" ::: "memory");
        __syncthreads();
        #pragma unroll
        for (int kk = 0; kk < 2; ++kk) {
            short8v av[4], bv[4];
            #pragma unroll
            for (int mi = 0; mi < 4; ++mi) {
                int m = wr * 64 + mi * 16 + l15;
                av[mi] = *(const short8v*)&Al[m * 64 + kk * 32 + lhi * 8];
            }
            #pragma unroll
            for (int ni = 0; ni < 4; ++ni) {
                int n = wc * 64 + ni * 16 + l15;
                bv[ni] = *(const short8v*)&Bl[n * 64 + kk * 32 + lhi * 8];
            }
            #pragma unroll
            for (int mi = 0; mi < 4; ++mi)
                #pragma unroll
                for (int ni = 0; ni < 4; ++ni)
                    acc[mi][ni] = __builtin_amdgcn_mfma_f32_16x16x32_bf16(av[mi], bv[ni], acc[mi][ni], 0, 0, 0);
        }
    }

    // epilogue: LDS transpose -> coalesced float4 stores (two 64-col halves)
    const unsigned bb = (unsigned)blockIdx.x;
    #pragma unroll
    for (int hhalf = 0; hhalf < 2; ++hhalf) {
        __syncthreads();
        if (wc == hhalf) {
            #pragma unroll
            for (int mi = 0; mi < 4; ++mi)
                #pragma unroll
                for (int ni = 0; ni < 4; ++ni)
                    #pragma unroll
                    for (int reg = 0; reg < 4; ++reg) {
                        int rl = wr * 64 + mi * 16 + lhi * 4 + reg;
                        int cl = ni * 16 + l15;
                        SMf[rl * 68 + cl] = acc[mi][ni][reg];
                    }
        }
        __syncthreads();
        int rl = tid >> 1;
        int cs = (tid & 1) * 32;
        int r = r0 + rl;
        if (r < RTOT) {
            unsigned base;
            if (r < KD) base = bb * 65536u + (unsigned)r * 128u;
            else        base = SREC_OFF + bb * 262656u + (unsigned)(r - KD) * 128u;
            base += hhalf * 64 + cs;
            const float* src = &SMf[rl * 68 + cs];
            float* dst = out + base;
            #pragma unroll
            for (int q = 0; q < 8; ++q)
                *(float4*)(dst + q * 4) = *(const float4*)(src + q * 4);
        }
    }
}

// ---------- Gram via MFMA: G = Y Y^T partials; grid (tj, ti, sk) ----------
__global__ __launch_bounds__(256) void k_gram(const ushort_t* __restrict__ Ybf, float* __restrict__ Pg) {
    __shared__ ushort_t SM2[16384];
    ushort_t* Al = SM2;
    ushort_t* Bl = SM2 + 8192;
    const int tid = threadIdx.x;
    const int wave = tid >> 6;
    const int lane = tid & 63;
    const int j0 = blockIdx.x * 128;
    const int i0 = blockIdx.y * 128;
    const int kc0 = blockIdx.z * 256;
    const int wr = wave >> 1, wc = wave & 1;
    const int l15 = lane & 15;
    const int lhi = lane >> 4;

    f32x4 acc[4][4];
    #pragma unroll
    for (int i = 0; i < 4; ++i)
        #pragma unroll
        for (int j = 0; j < 4; ++j)
            acc[i][j] = (f32x4){0.f, 0.f, 0.f, 0.f};

    for (int kc = kc0; kc < kc0 + 256; kc += 64) {
        __syncthreads();
        #pragma unroll
        for (int i = 0; i < 4; ++i) {
            int elt = (wave * 4 + i) * 64 + lane;
            int m = elt >> 3;
            int kb = (elt & 7) * 8;
            const ushort_t* ga = Ybf + (size_t)(i0 + m) * JTOT + kc + kb;
            const ushort_t* gb = Ybf + (size_t)(j0 + m) * JTOT + kc + kb;
            GLOAD16(ga, &Al[(wave * 4 + i) * 512]);
            GLOAD16(gb, &Bl[(wave * 4 + i) * 512]);
        }
        asm volatile("s_waitcnt vmcnt(0)" ::: "memory");
        __syncthreads();
        #pragma unroll
        for (int kk = 0; kk < 2; ++kk) {
            short8v av[4], bv[4];
            #pragma unroll
            for (int mi = 0; mi < 4; ++mi)
                av[mi] = *(const short8v*)&Al[(wr * 64 + mi * 16 + l15) * 64 + kk * 32 + lhi * 8];
            #pragma unroll
            for (int ni = 0; ni < 4; ++ni)
                bv[ni] = *(const short8v*)&Bl[(wc * 64 + ni * 16 + l15) * 64 + kk * 32 + lhi * 8];
            #pragma unroll
            for (int mi = 0; mi < 4; ++mi)
                #pragma unroll
                for (int ni = 0; ni < 4; ++ni)
                    acc[mi][ni] = __builtin_amdgcn_mfma_f32_16x16x32_bf16(av[mi], bv[ni], acc[mi][ni], 0, 0, 0);
        }
    }

    const int q = blockIdx.y * 2 + blockIdx.x;
    float* P = Pg + (size_t)(blockIdx.z * 4 + q) * 16384;
    #pragma unroll
    for (int mi = 0; mi < 4; ++mi)
        #pragma unroll
        for (int reg = 0; reg < 4; ++reg) {
            int rl = wr * 64 + mi * 16 + lhi * 4 + reg;
            #pragma unroll
            for (int ni = 0; ni < 4; ++ni) {
                int cl = wc * 64 + ni * 16 + l15;
                P[rl * 128 + cl] = acc[mi][ni][reg];
            }
        }
}

// ---------- combine Gram partials -> plv -> a; x = mean_b z ----------
__global__ __launch_bounds__(256) void k_plvx(const float* __restrict__ Pg, const float* __restrict__ z,
                                              float* __restrict__ A, float* __restrict__ X) {
    int id = blockIdx.x * 256 + threadIdx.x;  // 16384
    float R = 0.f, I = 0.f;
    #pragma unroll 8
    for (int sk = 0; sk < 32; ++sk) {
        const float* P = Pg + (size_t)sk * 65536 + id;
        R += P[0] + P[3 * 16384];
        I += P[2 * 16384] - P[1 * 16384];
    }
    float plv = sqrtf(R * R + I * I) * (1.0f / 8192.0f);
    A[id] = (plv >= 0.5f) ? 1.0f : 0.0f;
    float s = 0.f;
    for (int b = 0; b < 64; ++b) s += z[(size_t)b * 16384 + id];
    X[id] = s * (1.0f / 64.0f);
}

// ---------- ax = a @ x ----------
__global__ __launch_bounds__(256) void k_ax(const float* __restrict__ A, const float* __restrict__ X,
                                            float* __restrict__ AX) {
    int id = blockIdx.x * 256 + threadIdx.x;  // 16384
    int i = id >> 7, t = id & 127;
    float s = 0.f;
    for (int j = 0; j < 128; ++j) s += A[i * 128 + j] * X[j * 128 + t];
    AX[id] = s;
}

// ---------- hg = relu(ax @ w_gae + b_gae) ----------
__global__ __launch_bounds__(256) void k_hg(const float* __restrict__ AX, const float* __restrict__ Wg,
                                            const float* __restrict__ bg, float* __restrict__ HG) {
    int id = blockIdx.x * 256 + threadIdx.x;  // 8192
    int i = id >> 6, h = id & 63;
    float s = bg[h];
    for (int t = 0; t < 128; ++t) s += AX[i * 128 + t] * Wg[t * 64 + h];
    HG[id] = fmaxf(s, 0.f);
}

// ---------- a_aug ----------
__global__ __launch_bounds__(256) void k_aaug(const float* __restrict__ HG, const float* __restrict__ A,
                                              const float* __restrict__ U, float* __restrict__ out) {
    int id = blockIdx.x * 256 + threadIdx.x;  // 16384
    int i = id >> 7, j = id & 127;
    float dot = 0.f;
    #pragma unroll 8
    for (int h = 0; h < 64; ++h) dot += HG[i * 64 + h] * HG[j * 64 + h];
    float p = 1.f / (1.f + expf(-dot));
    float e = 0.5f * p + 0.5f * A[id];
    float gmb = -logf(-logf(U[id]));
    float arg = (logf(e) - logf(1.f - e) + gmb) * 10.0f;
    out[AAUG_OFF + id] = 1.f / (1.f + expf(-arg));
}

extern "C" void kernel_launch(void* const* d_in, const int* in_sizes, int n_in,
                              void* d_out, int out_size, void* d_ws, size_t ws_size,
                              hipStream_t stream) {
    const float* z  = (const float*)d_in[0];
    const float* LF = (const float*)d_in[1];
    const float* U  = (const float*)d_in[2];
    const float* Wg = (const float*)d_in[3];
    const float* bg = (const float*)d_in[4];
    float* out = (float*)d_out;
    float* W = (float*)d_ws;

    float* AF  = W + OFF_AF;
    ushort_t* Abf = (ushort_t*)(W + OFF_ABF);
    ushort_t* Bbf = (ushort_t*)(W + OFF_BBF);
    ushort_t* Ybf = (ushort_t*)(W + OFF_YBF);
    float* Pm1 = W + OFF_YBF;     // same region, consumed before Ybf is written
    float* Pg  = W + OFF_PG;
    float* A   = W + OFF_A;
    float* X   = W + OFF_X;
    float* AX  = W + OFF_AX;
    float* HG  = W + OFF_HG;

    k_m1   <<<dim3(64, 16), 256, 0, stream>>>(LF, Pm1);
    k_m1red<<<256, 256, 0, stream>>>(Pm1, AF, Abf);
    k_m2   <<<1026, 256, 0, stream>>>(AF, Abf);
    k_hilb <<<4096, 256, 0, stream>>>(z, Ybf, Bbf);
    k_gemm <<<dim3(64, 21), 256, 0, stream>>>(Abf, Bbf, out);
    k_gram <<<dim3(2, 2, 32), 256, 0, stream>>>(Ybf, Pg);
    k_plvx <<<64, 256, 0, stream>>>(Pg, z, A, X);
    k_ax   <<<64, 256, 0, stream>>>(A, X, AX);
    k_hg   <<<32, 256, 0, stream>>>(AX, Wg, bg, HG);
    k_aaug <<<64, 256, 0, stream>>>(HG, A, U, out);
}

// Round 5
// 121.241 us; speedup vs baseline: 2.3423x; 1.1359x over previous
//
#include <hip/hip_runtime.h>

#define NV 2052
#define KD 512
#define RTOT 2564
#define KTOT 256
#define JTOT 8192

typedef __attribute__((ext_vector_type(8))) short short8v;
typedef __attribute__((ext_vector_type(4))) float f32x4;
typedef unsigned short ushort_t;

// ws float offsets
#define OFF_AF   0u          // fp32 M1 rows [512][128]
#define OFF_ABF  65536u      // bf16 A' [2688][256]
#define OFF_BBF  581632u     // bf16 B' [8192][256]
#define OFF_YBF  2154496u    // bf16 Y  [256][8192]  (also Pm1 partials before hilb)
#define OFF_PG   3203072u    // fp32 Gram partials [32][4][128][128]
#define OFF_A    5300224u
#define OFF_X    5316608u
#define OFF_AX   5332992u
#define OFF_HG   5349376u

#define SREC_OFF 4194304u
#define AAUG_OFF 21004288u

#define GLOAD16(g, l) __builtin_amdgcn_global_load_lds( \
    (const __attribute__((address_space(1))) unsigned int*)(g), \
    (__attribute__((address_space(3))) unsigned int*)(l), 16, 0, 0)

__device__ __forceinline__ float dct_val(int k, int v) {
    if (k == 0) return 1.0f / sqrtf(2052.0f);
    int m = (2 * v + 1) * k;
    int r = m % 8208;                       // exact arg reduction mod 2*pi
    float ang = (float)((double)r * (3.14159265358979323846 / 4104.0));
    return sqrtf(2.0f / 2052.0f) * cosf(ang);
}

__device__ __forceinline__ void bf16split(float x, ushort_t& hi, ushort_t& lo) {
    unsigned xb = __float_as_uint(x);
    hi = (ushort_t)(xb >> 16);
    float r = x - __uint_as_float((unsigned)hi << 16);
    lo = (ushort_t)(__float_as_uint(r) >> 16);
}

__device__ __forceinline__ ushort_t bf16rn(float x) {
    unsigned xb = __float_as_uint(x);
    return (ushort_t)((xb + 0x7fffu + ((xb >> 16) & 1u)) >> 16);
}

// ---------- M1 partials: grid (64 k-groups, 16 v-chunks) ----------
__global__ __launch_bounds__(256) void k_m1(const float* __restrict__ LF, float* __restrict__ Pm1) {
    __shared__ float sd[8][132];
    const int tid = threadIdx.x;
    const int t = tid & 127;
    const int kk = tid >> 7;       // 0/1
    const int k0 = blockIdx.x * 8;
    const int vch = blockIdx.y;
    const int v0 = vch * 128;
    const int nv = (vch == 15) ? 132 : 128;
    for (int p = tid; p < 1056; p += 256) {
        int rr = p / 132, cc = p - rr * 132;
        sd[rr][cc] = dct_val(k0 + rr, v0 + cc);
    }
    __syncthreads();
    const float* lf = LF + (size_t)v0 * 128 + t;
    float a0 = 0.f, a1 = 0.f, a2 = 0.f, a3 = 0.f;
    int vi = 0;
    for (; vi + 2 <= nv; vi += 2) {
        float l0 = lf[vi * 128], l1 = lf[vi * 128 + 128];
        a0 += sd[kk + 0][vi] * l0; a1 += sd[kk + 2][vi] * l0;
        a2 += sd[kk + 4][vi] * l0; a3 += sd[kk + 6][vi] * l0;
        a0 += sd[kk + 0][vi + 1] * l1; a1 += sd[kk + 2][vi + 1] * l1;
        a2 += sd[kk + 4][vi + 1] * l1; a3 += sd[kk + 6][vi + 1] * l1;
    }
    float* P = Pm1 + (size_t)vch * 65536;
    P[(k0 + kk + 0) * 128 + t] = a0;
    P[(k0 + kk + 2) * 128 + t] = a1;
    P[(k0 + kk + 4) * 128 + t] = a2;
    P[(k0 + kk + 6) * 128 + t] = a3;
}

// ---------- reduce partials -> AF fp32 rows 0..511 AND Abf bf16 (hi,lo) rows ----------
__global__ __launch_bounds__(256) void k_m1red(const float* __restrict__ Pm1, float* __restrict__ AF,
                                               ushort_t* __restrict__ Abf) {
    int id = blockIdx.x * 256 + threadIdx.x;  // 65536
    float s = 0.f;
    #pragma unroll
    for (int p = 0; p < 16; ++p) s += Pm1[p * 65536 + id];
    AF[id] = s;
    int rid = id >> 7, t = id & 127;
    ushort_t hi, lo; bf16split(s, hi, lo);
    ushort_t* row = Abf + (size_t)rid * KTOT;
    row[t] = hi; row[128 + t] = lo;
}

// ---------- M2 = dctT @ M1 -> Abf rows 512..2563 directly ----------
__global__ __launch_bounds__(256) void k_m2(const float* __restrict__ M1, ushort_t* __restrict__ Abf) {
    __shared__ float sd[2][128];
    const int tid = threadIdx.x;
    const int t = tid & 127;
    const int vv = tid >> 7;
    const int myv = blockIdx.x * 2 + vv;
    float a0 = 0.f, a1 = 0.f, a2 = 0.f, a3 = 0.f;
    for (int kc = 0; kc < KD; kc += 128) {
        __syncthreads();
        sd[vv][t] = dct_val(kc + t, myv);
        __syncthreads();
        const float* m1 = M1 + (size_t)kc * 128 + t;
        #pragma unroll 8
        for (int ki = 0; ki < 32; ++ki) {
            a0 += sd[vv][ki +  0] * m1[(ki +  0) * 128];
            a1 += sd[vv][ki + 32] * m1[(ki + 32) * 128];
            a2 += sd[vv][ki + 64] * m1[(ki + 64) * 128];
            a3 += sd[vv][ki + 96] * m1[(ki + 96) * 128];
        }
    }
    float s = (a0 + a1) + (a2 + a3);
    ushort_t hi, lo; bf16split(s, hi, lo);
    ushort_t* row = Abf + (size_t)(KD + myv) * KTOT;
    row[t] = hi; row[128 + t] = lo;
}

// ---------- Hilbert: emit Y bf16 AND B' bf16 (hi,hi) rows ----------
__global__ __launch_bounds__(256) void k_hilb(const float* __restrict__ z,
                                              ushort_t* __restrict__ Ybf, ushort_t* __restrict__ Bbf) {
    __shared__ float zr[2][128];
    __shared__ float h[128];
    const int tid = threadIdx.x;
    const int t = tid & 127;
    const int rr = tid >> 7;
    const int rid = blockIdx.x * 2 + rr;   // b*128+i
    const int b = rid >> 7, i = rid & 127;
    zr[rr][t] = z[(size_t)rid * 128 + t];
    if (tid < 128) {
        float hv = 0.f;
        if (t & 1) {
            float ang = 3.14159265358979323846f * (float)t * (1.0f / 128.0f);
            hv = (cosf(ang) / sinf(ang)) * (1.0f / 64.0f);
        }
        h[t] = hv;
    }
    __syncthreads();
    float acc = 0.f;
    #pragma unroll 8
    for (int q = 0; q < 64; ++q) {
        int d = 2 * q + 1;
        acc += h[d] * zr[rr][(t - d) & 127];
    }
    float zv = zr[rr][t];
    float inv = rsqrtf(zv * zv + acc * acc);
    Ybf[(size_t)i * JTOT + b * 128 + t] = bf16rn(zv * inv);
    Ybf[(size_t)(128 + i) * JTOT + b * 128 + t] = bf16rn(acc * inv);
    ushort_t hi = (ushort_t)(__float_as_uint(zv) >> 16);
    ushort_t* row = Bbf + (size_t)rid * KTOT;
    row[t] = hi; row[128 + t] = hi;
}

// ---------- MFMA GEMM: C[r][j] = sum_k' A'[r][k'] B'[j][k'], K'=256, swizzled LDS ----------
__global__ __launch_bounds__(256) void k_gemm(const ushort_t* __restrict__ Abf, const ushort_t* __restrict__ Bbf,
                                              float* __restrict__ out) {
    __shared__ float SMf[8704];            // 34816 B; Al+Bl (32KB) overlay, epilogue [128][68]
    ushort_t* Al = (ushort_t*)SMf;         // [128 rows][64 k] 16B-chunk-swizzled
    ushort_t* Bl = Al + 8192;
    const int tid = threadIdx.x;
    const int wave = tid >> 6;
    const int lane = tid & 63;
    const int j0 = blockIdx.x * 128;
    const int r0 = blockIdx.y * 128;
    const int wr = wave >> 1, wc = wave & 1;
    const int l15 = lane & 15;
    const int lhi = lane >> 4;

    f32x4 acc[4][4];
    #pragma unroll
    for (int i = 0; i < 4; ++i)
        #pragma unroll
        for (int j = 0; j < 4; ++j)
            acc[i][j] = (f32x4){0.f, 0.f, 0.f, 0.f};

    for (int kc = 0; kc < KTOT; kc += 64) {
        __syncthreads();
        #pragma unroll
        for (int i = 0; i < 4; ++i) {
            int elt = (wave * 4 + i) * 64 + lane;   // linear 16B-chunk id
            int m = elt >> 3;
            int c = elt & 7;
            int sc = c ^ (m & 7);                   // pre-swizzled source chunk
            const ushort_t* ga = Abf + (size_t)(r0 + m) * KTOT + kc + sc * 8;
            const ushort_t* gb = Bbf + (size_t)(j0 + m) * KTOT + kc + sc * 8;
            GLOAD16(ga, &Al[(wave * 4 + i) * 512]);
            GLOAD16(gb, &Bl[(wave * 4 + i) * 512]);
        }
        asm volatile("s_waitcnt vmcnt(0)" ::: "memory");
        __syncthreads();
        #pragma unroll
        for (int kk = 0; kk < 2; ++kk) {
            short8v av[4], bv[4];
            #pragma unroll
            for (int mi = 0; mi < 4; ++mi) {
                int m = wr * 64 + mi * 16 + l15;
                int ch = (kk * 4 + lhi) ^ (m & 7);
                av[mi] = *(const short8v*)&Al[m * 64 + ch * 8];
            }
            #pragma unroll
            for (int ni = 0; ni < 4; ++ni) {
                int n = wc * 64 + ni * 16 + l15;
                int ch = (kk * 4 + lhi) ^ (n & 7);
                bv[ni] = *(const short8v*)&Bl[n * 64 + ch * 8];
            }
            #pragma unroll
            for (int mi = 0; mi < 4; ++mi)
                #pragma unroll
                for (int ni = 0; ni < 4; ++ni)
                    acc[mi][ni] = __builtin_amdgcn_mfma_f32_16x16x32_bf16(av[mi], bv[ni], acc[mi][ni], 0, 0, 0);
        }
    }

    // epilogue: LDS transpose -> coalesced float4 stores (two 64-col halves)
    const unsigned bb = (unsigned)blockIdx.x;
    #pragma unroll
    for (int hhalf = 0; hhalf < 2; ++hhalf) {
        __syncthreads();
        if (wc == hhalf) {
            #pragma unroll
            for (int mi = 0; mi < 4; ++mi)
                #pragma unroll
                for (int ni = 0; ni < 4; ++ni)
                    #pragma unroll
                    for (int reg = 0; reg < 4; ++reg) {
                        int rl = wr * 64 + mi * 16 + lhi * 4 + reg;
                        int cl = ni * 16 + l15;
                        SMf[rl * 68 + cl] = acc[mi][ni][reg];
                    }
        }
        __syncthreads();
        int rl = tid >> 1;
        int cs = (tid & 1) * 32;
        int r = r0 + rl;
        if (r < RTOT) {
            unsigned base;
            if (r < KD) base = bb * 65536u + (unsigned)r * 128u;
            else        base = SREC_OFF + bb * 262656u + (unsigned)(r - KD) * 128u;
            base += hhalf * 64 + cs;
            const float* src = &SMf[rl * 68 + cs];
            float* dst = out + base;
            #pragma unroll
            for (int q = 0; q < 8; ++q)
                *(float4*)(dst + q * 4) = *(const float4*)(src + q * 4);
        }
    }
}

// ---------- Gram via MFMA: G = Y Y^T partials; grid (tj, ti, sk); swizzled LDS ----------
__global__ __launch_bounds__(256) void k_gram(const ushort_t* __restrict__ Ybf, float* __restrict__ Pg) {
    __shared__ ushort_t SM2[16384];
    ushort_t* Al = SM2;
    ushort_t* Bl = SM2 + 8192;
    const int tid = threadIdx.x;
    const int wave = tid >> 6;
    const int lane = tid & 63;
    const int j0 = blockIdx.x * 128;
    const int i0 = blockIdx.y * 128;
    const int kc0 = blockIdx.z * 256;
    const int wr = wave >> 1, wc = wave & 1;
    const int l15 = lane & 15;
    const int lhi = lane >> 4;

    f32x4 acc[4][4];
    #pragma unroll
    for (int i = 0; i < 4; ++i)
        #pragma unroll
        for (int j = 0; j < 4; ++j)
            acc[i][j] = (f32x4){0.f, 0.f, 0.f, 0.f};

    for (int kc = kc0; kc < kc0 + 256; kc += 64) {
        __syncthreads();
        #pragma unroll
        for (int i = 0; i < 4; ++i) {
            int elt = (wave * 4 + i) * 64 + lane;
            int m = elt >> 3;
            int c = elt & 7;
            int sc = c ^ (m & 7);
            const ushort_t* ga = Ybf + (size_t)(i0 + m) * JTOT + kc + sc * 8;
            const ushort_t* gb = Ybf + (size_t)(j0 + m) * JTOT + kc + sc * 8;
            GLOAD16(ga, &Al[(wave * 4 + i) * 512]);
            GLOAD16(gb, &Bl[(wave * 4 + i) * 512]);
        }
        asm volatile("s_waitcnt vmcnt(0)" ::: "memory");
        __syncthreads();
        #pragma unroll
        for (int kk = 0; kk < 2; ++kk) {
            short8v av[4], bv[4];
            #pragma unroll
            for (int mi = 0; mi < 4; ++mi) {
                int m = wr * 64 + mi * 16 + l15;
                int ch = (kk * 4 + lhi) ^ (m & 7);
                av[mi] = *(const short8v*)&Al[m * 64 + ch * 8];
            }
            #pragma unroll
            for (int ni = 0; ni < 4; ++ni) {
                int n = wc * 64 + ni * 16 + l15;
                int ch = (kk * 4 + lhi) ^ (n & 7);
                bv[ni] = *(const short8v*)&Bl[n * 64 + ch * 8];
            }
            #pragma unroll
            for (int mi = 0; mi < 4; ++mi)
                #pragma unroll
                for (int ni = 0; ni < 4; ++ni)
                    acc[mi][ni] = __builtin_amdgcn_mfma_f32_16x16x32_bf16(av[mi], bv[ni], acc[mi][ni], 0, 0, 0);
        }
    }

    const int q = blockIdx.y * 2 + blockIdx.x;
    float* P = Pg + (size_t)(blockIdx.z * 4 + q) * 16384;
    #pragma unroll
    for (int mi = 0; mi < 4; ++mi)
        #pragma unroll
        for (int reg = 0; reg < 4; ++reg) {
            int rl = wr * 64 + mi * 16 + lhi * 4 + reg;
            #pragma unroll
            for (int ni = 0; ni < 4; ++ni) {
                int cl = wc * 64 + ni * 16 + l15;
                P[rl * 128 + cl] = acc[mi][ni][reg];
            }
        }
}

// ---------- combine Gram partials -> plv -> a; x = mean_b z ----------
__global__ __launch_bounds__(256) void k_plvx(const float* __restrict__ Pg, const float* __restrict__ z,
                                              float* __restrict__ A, float* __restrict__ X) {
    int id = blockIdx.x * 256 + threadIdx.x;  // 16384
    float R = 0.f, I = 0.f;
    #pragma unroll 8
    for (int sk = 0; sk < 32; ++sk) {
        const float* P = Pg + (size_t)sk * 65536 + id;
        R += P[0] + P[3 * 16384];
        I += P[2 * 16384] - P[1 * 16384];
    }
    float plv = sqrtf(R * R + I * I) * (1.0f / 8192.0f);
    A[id] = (plv >= 0.5f) ? 1.0f : 0.0f;
    float s = 0.f;
    for (int b = 0; b < 64; ++b) s += z[(size_t)b * 16384 + id];
    X[id] = s * (1.0f / 64.0f);
}

// ---------- ax = a @ x ----------
__global__ __launch_bounds__(256) void k_ax(const float* __restrict__ A, const float* __restrict__ X,
                                            float* __restrict__ AX) {
    int id = blockIdx.x * 256 + threadIdx.x;  // 16384
    int i = id >> 7, t = id & 127;
    float s = 0.f;
    for (int j = 0; j < 128; ++j) s += A[i * 128 + j] * X[j * 128 + t];
    AX[id] = s;
}

// ---------- hg = relu(ax @ w_gae + b_gae) ----------
__global__ __launch_bounds__(256) void k_hg(const float* __restrict__ AX, const float* __restrict__ Wg,
                                            const float* __restrict__ bg, float* __restrict__ HG) {
    int id = blockIdx.x * 256 + threadIdx.x;  // 8192
    int i = id >> 6, h = id & 63;
    float s = bg[h];
    for (int t = 0; t < 128; ++t) s += AX[i * 128 + t] * Wg[t * 64 + h];
    HG[id] = fmaxf(s, 0.f);
}

// ---------- a_aug ----------
__global__ __launch_bounds__(256) void k_aaug(const float* __restrict__ HG, const float* __restrict__ A,
                                              const float* __restrict__ U, float* __restrict__ out) {
    int id = blockIdx.x * 256 + threadIdx.x;  // 16384
    int i = id >> 7, j = id & 127;
    float dot = 0.f;
    #pragma unroll 8
    for (int h = 0; h < 64; ++h) dot += HG[i * 64 + h] * HG[j * 64 + h];
    float p = 1.f / (1.f + expf(-dot));
    float e = 0.5f * p + 0.5f * A[id];
    float gmb = -logf(-logf(U[id]));
    float arg = (logf(e) - logf(1.f - e) + gmb) * 10.0f;
    out[AAUG_OFF + id] = 1.f / (1.f + expf(-arg));
}

extern "C" void kernel_launch(void* const* d_in, const int* in_sizes, int n_in,
                              void* d_out, int out_size, void* d_ws, size_t ws_size,
                              hipStream_t stream) {
    const float* z  = (const float*)d_in[0];
    const float* LF = (const float*)d_in[1];
    const float* U  = (const float*)d_in[2];
    const float* Wg = (const float*)d_in[3];
    const float* bg = (const float*)d_in[4];
    float* out = (float*)d_out;
    float* W = (float*)d_ws;

    float* AF  = W + OFF_AF;
    ushort_t* Abf = (ushort_t*)(W + OFF_ABF);
    ushort_t* Bbf = (ushort_t*)(W + OFF_BBF);
    ushort_t* Ybf = (ushort_t*)(W + OFF_YBF);
    float* Pm1 = W + OFF_YBF;     // same region, consumed before Ybf is written
    float* Pg  = W + OFF_PG;
    float* A   = W + OFF_A;
    float* X   = W + OFF_X;
    float* AX  = W + OFF_AX;
    float* HG  = W + OFF_HG;

    k_m1   <<<dim3(64, 16), 256, 0, stream>>>(LF, Pm1);
    k_m1red<<<256, 256, 0, stream>>>(Pm1, AF, Abf);
    k_m2   <<<1026, 256, 0, stream>>>(AF, Abf);
    k_hilb <<<4096, 256, 0, stream>>>(z, Ybf, Bbf);
    k_gemm <<<dim3(64, 21), 256, 0, stream>>>(Abf, Bbf, out);
    k_gram <<<dim3(2, 2, 32), 256, 0, stream>>>(Ybf, Pg);
    k_plvx <<<64, 256, 0, stream>>>(Pg, z, A, X);
    k_ax   <<<64, 256, 0, stream>>>(A, X, AX);
    k_hg   <<<32, 256, 0, stream>>>(AX, Wg, bg, HG);
    k_aaug <<<64, 256, 0, stream>>>(HG, A, U, out);
}